// Round 1
// baseline (1066.069 us; speedup 1.0000x reference)
//
#include <hip/hip_runtime.h>

#define D 128
#define BN 16
#define HALF 64
#define WPAD 68
#define XPAD 132

// Kernel 1: h = relu(x @ W^T + b) * (mask_u >= 0.5) * 2
// Persistent blocks; each block owns one half (64 cols) of W staged
// transposed in LDS; grid-strides over 16-node tiles.
__global__ __launch_bounds__(256, 3) void gemm_relu_drop_kernel(
    const float* __restrict__ x, const float* __restrict__ W,
    const float* __restrict__ bias, const float* __restrict__ mask_u,
    float* __restrict__ h, int n_nodes)
{
    __shared__ float Wt[D][WPAD];   // 128*68*4 = 34816 B, Wt[d][o'] = W[o_base+o'][d]
    __shared__ float xs[BN][XPAD];  // 16*132*4 = 8448 B
    const int t = threadIdx.x;
    const int half  = blockIdx.x & 1;
    const int bslot = blockIdx.x >> 1;
    const int nb    = gridDim.x >> 1;
    const int o_base = half * HALF;

    // Stage W half, transposed (coalesced global reads).
    for (int i = t; i < HALF * D; i += 256) {
        int o = i >> 7;          // 0..63
        int d = i & (D - 1);     // 0..127
        Wt[d][o] = W[(o_base + o) * D + d];
    }

    const int nl = t >> 4;       // node-local 0..15
    const int m  = t & 15;       // output group: cols 4m..4m+3
    const float4 b4 = *(const float4*)&bias[o_base + 4 * m];

    const int n_tiles = (n_nodes + BN - 1) / BN;
    for (int tile = bslot; tile < n_tiles; tile += nb) {
        __syncthreads();   // previous tile's compute done (also covers W staging)
        const int n0 = tile * BN;
        // Stage 16 x-rows as float4 (coalesced).
        for (int i = t; i < (BN * D) / 4; i += 256) {
            int n  = i >> 5;           // 0..15
            int d4 = (i & 31) * 4;     // 0..124
            int gn = n0 + n;
            float4 v = (gn < n_nodes) ? *(const float4*)&x[(size_t)gn * D + d4]
                                      : make_float4(0.f, 0.f, 0.f, 0.f);
            *(float4*)&xs[n][d4] = v;
        }
        __syncthreads();

        float4 acc = make_float4(0.f, 0.f, 0.f, 0.f);
        #pragma unroll 8
        for (int d = 0; d < D; ++d) {
            float  xv = xs[nl][d];                     // broadcast, conflict-free (pad 132)
            float4 w4 = *(const float4*)&Wt[d][4 * m]; // b128, 2-way alias (free)
            acc.x = fmaf(xv, w4.x, acc.x);
            acc.y = fmaf(xv, w4.y, acc.y);
            acc.z = fmaf(xv, w4.z, acc.z);
            acc.w = fmaf(xv, w4.w, acc.w);
        }

        const int gn = n0 + nl;
        if (gn < n_nodes) {
            const size_t off = (size_t)gn * D + o_base + 4 * m;
            float4 mk = *(const float4*)&mask_u[off];
            float4 r;
            r.x = fmaxf(acc.x + b4.x, 0.f) * (mk.x >= 0.5f ? 2.f : 0.f);
            r.y = fmaxf(acc.y + b4.y, 0.f) * (mk.y >= 0.5f ? 2.f : 0.f);
            r.z = fmaxf(acc.z + b4.z, 0.f) * (mk.z >= 0.5f ? 2.f : 0.f);
            r.w = fmaxf(acc.w + b4.w, 0.f) * (mk.w >= 0.5f ? 2.f : 0.f);
            *(float4*)&h[off] = r;
        }
    }
}

// Kernel 2: out[dst[e]] += h[src[e]]  (32 lanes per edge, float4 gather)
__global__ __launch_bounds__(256) void scatter_kernel(
    const float* __restrict__ h, const int* __restrict__ src,
    const int* __restrict__ dst, float* __restrict__ out, int n_edges)
{
    const int t = threadIdx.x;
    const int e = blockIdx.x * 8 + (t >> 5);
    if (e >= n_edges) return;
    const int c = (t & 31) * 4;
    const int s  = src[e];
    const int dd = dst[e];
    float4 v = *(const float4*)&h[(size_t)s * D + c];
    float* o = &out[(size_t)dd * D + c];
    atomicAdd(o + 0, v.x);
    atomicAdd(o + 1, v.y);
    atomicAdd(o + 2, v.z);
    atomicAdd(o + 3, v.w);
}

extern "C" void kernel_launch(void* const* d_in, const int* in_sizes, int n_in,
                              void* d_out, int out_size, void* d_ws, size_t ws_size,
                              hipStream_t stream) {
    const float* x      = (const float*)d_in[0];
    const float* W      = (const float*)d_in[1];
    const float* bias   = (const float*)d_in[2];
    const float* mask_u = (const float*)d_in[3];
    const int*   src    = (const int*)d_in[4];
    const int*   dst    = (const int*)d_in[5];
    float* out = (float*)d_out;
    float* h   = (float*)d_ws;   // 50000*128*4 = 25.6 MB scratch

    const int n_nodes = in_sizes[0] / D;
    const int n_edges = in_sizes[4];

    // Harness poisons d_out once and never re-poisons: zero it every call.
    hipMemsetAsync(d_out, 0, (size_t)out_size * sizeof(float), stream);

    gemm_relu_drop_kernel<<<768, 256, 0, stream>>>(x, W, bias, mask_u, h, n_nodes);

    const int blocks = (n_edges + 7) / 8;
    scatter_kernel<<<blocks, 256, 0, stream>>>(h, src, dst, out, n_edges);
}

// Round 2
// 165.667 us; speedup vs baseline: 6.4350x; 6.4350x over previous
//
#include <hip/hip_runtime.h>

#define D 128
#define BN 16
#define HALF 64
#define WPAD 68
#define XPAD 132

// ---------------- Kernel 1: h = relu(x @ W^T + b) * (mask_u >= 0.5) * 2 ----
__global__ __launch_bounds__(256, 3) void gemm_relu_drop_kernel(
    const float* __restrict__ x, const float* __restrict__ W,
    const float* __restrict__ bias, const float* __restrict__ mask_u,
    float* __restrict__ h, int n_nodes)
{
    __shared__ float Wt[D][WPAD];   // Wt[d][o'] = W[o_base+o'][d]
    __shared__ float xs[BN][XPAD];
    const int t = threadIdx.x;
    const int half  = blockIdx.x & 1;
    const int bslot = blockIdx.x >> 1;
    const int nb    = gridDim.x >> 1;
    const int o_base = half * HALF;

    for (int i = t; i < HALF * D; i += 256) {
        int o = i >> 7;
        int d = i & (D - 1);
        Wt[d][o] = W[(o_base + o) * D + d];
    }

    const int nl = t >> 4;
    const int m  = t & 15;
    const float4 b4 = *(const float4*)&bias[o_base + 4 * m];

    const int n_tiles = (n_nodes + BN - 1) / BN;
    for (int tile = bslot; tile < n_tiles; tile += nb) {
        __syncthreads();
        const int n0 = tile * BN;
        for (int i = t; i < (BN * D) / 4; i += 256) {
            int n  = i >> 5;
            int d4 = (i & 31) * 4;
            int gn = n0 + n;
            float4 v = (gn < n_nodes) ? *(const float4*)&x[(size_t)gn * D + d4]
                                      : make_float4(0.f, 0.f, 0.f, 0.f);
            *(float4*)&xs[n][d4] = v;
        }
        __syncthreads();

        float4 acc = make_float4(0.f, 0.f, 0.f, 0.f);
        #pragma unroll 8
        for (int d = 0; d < D; ++d) {
            float  xv = xs[nl][d];
            float4 w4 = *(const float4*)&Wt[d][4 * m];
            acc.x = fmaf(xv, w4.x, acc.x);
            acc.y = fmaf(xv, w4.y, acc.y);
            acc.z = fmaf(xv, w4.z, acc.z);
            acc.w = fmaf(xv, w4.w, acc.w);
        }

        const int gn = n0 + nl;
        if (gn < n_nodes) {
            const size_t off = (size_t)gn * D + o_base + 4 * m;
            float4 mk = *(const float4*)&mask_u[off];
            float4 r;
            r.x = fmaxf(acc.x + b4.x, 0.f) * (mk.x >= 0.5f ? 2.f : 0.f);
            r.y = fmaxf(acc.y + b4.y, 0.f) * (mk.y >= 0.5f ? 2.f : 0.f);
            r.z = fmaxf(acc.z + b4.z, 0.f) * (mk.z >= 0.5f ? 2.f : 0.f);
            r.w = fmaxf(acc.w + b4.w, 0.f) * (mk.w >= 0.5f ? 2.f : 0.f);
            *(float4*)&h[off] = r;
        }
    }
}

// ---------------- CSR build: histogram -> exclusive scan -> bucket scatter --
__global__ __launch_bounds__(256) void hist_kernel(
    const int* __restrict__ dst, int* __restrict__ cnt, int n_edges)
{
    int i = blockIdx.x * 256 + threadIdx.x;
    if (i < n_edges) atomicAdd(&cnt[dst[i]], 1);
}

__global__ __launch_bounds__(256) void scan_partial_kernel(
    const int* __restrict__ cnt, int* __restrict__ bsum, int n)
{
    __shared__ int s[256];
    int t = threadIdx.x;
    int i = blockIdx.x * 256 + t;
    s[t] = (i < n) ? cnt[i] : 0;
    __syncthreads();
    for (int o = 128; o > 0; o >>= 1) {
        if (t < o) s[t] += s[t + o];
        __syncthreads();
    }
    if (t == 0) bsum[blockIdx.x] = s[0];
}

__global__ __launch_bounds__(256) void scan_bsum_kernel(int* __restrict__ bsum, int nb)
{
    __shared__ int s[256];
    int t = threadIdx.x;
    int v = (t < nb) ? bsum[t] : 0;
    s[t] = v;
    __syncthreads();
    for (int o = 1; o < 256; o <<= 1) {
        int add = (t >= o) ? s[t - o] : 0;
        __syncthreads();
        s[t] += add;
        __syncthreads();
    }
    if (t < nb) bsum[t] = s[t] - v;   // exclusive
}

// in-place: offs[i] = exclusive_prefix_sum(cnt)[i]
__global__ __launch_bounds__(256) void scan_final_kernel(
    int* __restrict__ offs, const int* __restrict__ bsum, int n)
{
    __shared__ int s[256];
    int t = threadIdx.x;
    int i = blockIdx.x * 256 + t;
    int v = (i < n) ? offs[i] : 0;
    s[t] = v;
    __syncthreads();
    for (int o = 1; o < 256; o <<= 1) {
        int add = (t >= o) ? s[t - o] : 0;
        __syncthreads();
        s[t] += add;
        __syncthreads();
    }
    if (i < n) offs[i] = s[t] - v + bsum[blockIdx.x];
}

// scatter src into dst-buckets; offs[n] becomes end_n (= start_{n+1}) after.
__global__ __launch_bounds__(256) void scatter_build_kernel(
    const int* __restrict__ src, const int* __restrict__ dst,
    int* __restrict__ offs, int* __restrict__ srcs, int n_edges)
{
    int i = blockIdx.x * 256 + threadIdx.x;
    if (i < n_edges) {
        int pos = atomicAdd(&offs[dst[i]], 1);
        srcs[pos] = src[i];
    }
}

// ---------------- Gather-reduce: out[n] = sum over incoming edges of h[src] -
__global__ __launch_bounds__(256) void gather_reduce_kernel(
    const float* __restrict__ h, const int* __restrict__ srcs,
    const int* __restrict__ offs, float* __restrict__ out, int n_nodes)
{
    const int t = threadIdx.x;
    const int node = blockIdx.x * 8 + (t >> 5);
    if (node >= n_nodes) return;
    const int c = (t & 31) * 4;
    const int start = (node == 0) ? 0 : offs[node - 1];
    const int end   = offs[node];
    float4 acc = make_float4(0.f, 0.f, 0.f, 0.f);
    for (int i = start; i < end; ++i) {
        int s = srcs[i];
        float4 v = *(const float4*)&h[(size_t)s * D + c];
        acc.x += v.x; acc.y += v.y; acc.z += v.z; acc.w += v.w;
    }
    *(float4*)&out[(size_t)node * D + c] = acc;
}

// ---------------- Fallback: direct atomic scatter ---------------------------
__global__ __launch_bounds__(256) void scatter_atomic_kernel(
    const float* __restrict__ h, const int* __restrict__ src,
    const int* __restrict__ dst, float* __restrict__ out, int n_edges)
{
    const int t = threadIdx.x;
    const int e = blockIdx.x * 8 + (t >> 5);
    if (e >= n_edges) return;
    const int c = (t & 31) * 4;
    const int s  = src[e];
    const int dd = dst[e];
    float4 v = *(const float4*)&h[(size_t)s * D + c];
    float* o = &out[(size_t)dd * D + c];
    atomicAdd(o + 0, v.x);
    atomicAdd(o + 1, v.y);
    atomicAdd(o + 2, v.z);
    atomicAdd(o + 3, v.w);
}

extern "C" void kernel_launch(void* const* d_in, const int* in_sizes, int n_in,
                              void* d_out, int out_size, void* d_ws, size_t ws_size,
                              hipStream_t stream) {
    const float* x      = (const float*)d_in[0];
    const float* W      = (const float*)d_in[1];
    const float* bias   = (const float*)d_in[2];
    const float* mask_u = (const float*)d_in[3];
    const int*   src    = (const int*)d_in[4];
    const int*   dst    = (const int*)d_in[5];
    float* out = (float*)d_out;

    const int n_nodes = in_sizes[0] / D;
    const int n_edges = in_sizes[4];

    // ws layout
    const size_t h_bytes    = (size_t)n_nodes * D * sizeof(float);
    float* h    = (float*)d_ws;
    int*   offs = (int*)((char*)d_ws + h_bytes);              // n_nodes ints
    int*   bsum = offs + n_nodes;                             // 256 ints
    int*   srcs = bsum + 256;                                 // n_edges ints
    const size_t needed = h_bytes + ((size_t)n_nodes + 256 + n_edges) * sizeof(int);

    gemm_relu_drop_kernel<<<768, 256, 0, stream>>>(x, W, bias, mask_u, h, n_nodes);

    const int eb = (n_edges + 255) / 256;        // edge-parallel blocks
    const int nbk = (n_nodes + 255) / 256;       // node-chunk blocks (<=256 req)

    if (ws_size >= needed && nbk <= 256) {
        // CSR build (counts -> exclusive scan in-place -> bucket scatter)
        hipMemsetAsync(offs, 0, (size_t)n_nodes * sizeof(int), stream);
        hist_kernel<<<eb, 256, 0, stream>>>(dst, offs, n_edges);
        scan_partial_kernel<<<nbk, 256, 0, stream>>>(offs, bsum, n_nodes);
        scan_bsum_kernel<<<1, 256, 0, stream>>>(bsum, nbk);
        scan_final_kernel<<<nbk, 256, 0, stream>>>(offs, bsum, n_nodes);
        scatter_build_kernel<<<eb, 256, 0, stream>>>(src, dst, offs, srcs, n_edges);
        // after scatter, offs[n] == end_n; reduce writes every out element
        gather_reduce_kernel<<<(n_nodes + 7) / 8, 256, 0, stream>>>(
            h, srcs, offs, out, n_nodes);
    } else {
        hipMemsetAsync(d_out, 0, (size_t)out_size * sizeof(float), stream);
        scatter_atomic_kernel<<<(n_edges + 7) / 8, 256, 0, stream>>>(
            h, src, dst, out, n_edges);
    }
}